// Round 3
// baseline (866.749 us; speedup 1.0000x reference)
//
#include <hip/hip_runtime.h>
#include <hip/hip_bf16.h>
#include <math.h>

typedef __attribute__((ext_vector_type(8))) short short8;
typedef __attribute__((ext_vector_type(4))) float f32x4;

__device__ inline ushort f2bf(float f) {
    uint u = __builtin_bit_cast(uint, f);
    u += 0x7fffu + ((u >> 16) & 1u);          // round-to-nearest-even
    return (ushort)(u >> 16);
}
__device__ inline float bf2f(ushort h) {
    return __builtin_bit_cast(float, (uint)h << 16);
}

// ---------------- degree / CSR build ----------------

__global__ __launch_bounds__(256) void count_kernel(const int* __restrict__ dst, int* __restrict__ cnt, int E) {
    for (int e = blockIdx.x * blockDim.x + threadIdx.x; e < E; e += gridDim.x * blockDim.x)
        atomicAdd(&cnt[dst[e]], 1);
}

__global__ __launch_bounds__(256) void dinv_kernel(const int* __restrict__ cnt, float* __restrict__ dinv, int N) {
    int i = blockIdx.x * 256 + threadIdx.x;
    if (i < N) dinv[i] = rsqrtf((float)(cnt[i] + 1));   // +1 self loop; deg >= 1 always
}

__global__ __launch_bounds__(1024) void scan_kernel(const int* __restrict__ cnt, int* __restrict__ offs, int N) {
    __shared__ int part[1024];
    int tid = threadIdx.x;
    int chunk = (N + 1023) / 1024;
    int beg = tid * chunk;
    int end = beg + chunk; if (end > N) end = N;
    int s = 0;
    for (int i = beg; i < end; ++i) s += cnt[i];
    part[tid] = s;
    __syncthreads();
    for (int off = 1; off < 1024; off <<= 1) {
        int t = (tid >= off) ? part[tid - off] : 0;
        __syncthreads();
        part[tid] += t;
        __syncthreads();
    }
    int run = (tid > 0) ? part[tid - 1] : 0;
    for (int i = beg; i < end; ++i) { offs[i] = run; run += cnt[i]; }
    if (beg < N && end == N) offs[N] = run;
}

__global__ __launch_bounds__(256) void scatter_kernel(const int* __restrict__ src, const int* __restrict__ dst,
                                                      const int* __restrict__ offs, int* __restrict__ cursor,
                                                      int* __restrict__ csr, int E) {
    for (int e = blockIdx.x * blockDim.x + threadIdx.x; e < E; e += gridDim.x * blockDim.x) {
        int d = dst[e];
        int p = atomicAdd(&cursor[d], 1);
        csr[offs[d] + p] = src[e];
    }
}

// ---------------- weight prep: Wt[128][512] bf16 (transposed), bcat[128], W3s[32*40], b3s[40] ----

__global__ __launch_bounds__(256) void prep_kernel(const float* __restrict__ W1a, const float* __restrict__ W1b,
                                                   const float* __restrict__ W2a, const float* __restrict__ W2b,
                                                   const float* __restrict__ b1a, const float* __restrict__ b1b,
                                                   const float* __restrict__ b2a, const float* __restrict__ b2b,
                                                   const float* __restrict__ W3a, const float* __restrict__ W3b,
                                                   const float* __restrict__ b3a, const float* __restrict__ b3b,
                                                   ushort* __restrict__ Wt, float* __restrict__ bcat,
                                                   float* __restrict__ W3s, float* __restrict__ b3s) {
    int idx = blockIdx.x * 256 + threadIdx.x;
    if (idx < 128 * 512) {
        int c = idx >> 9, k = idx & 511;   // Wt[c][k] = Wcat[k][c]
        const float* W = (c < 32) ? W1a : (c < 64) ? W1b : (c < 96) ? W2a : W2b;
        Wt[idx] = f2bf(W[k * 32 + (c & 31)]);
    }
    if (idx < 1280) W3s[idx] = W3a[idx] + W3b[idx];
    if (idx < 128) {
        const float* b = (idx < 32) ? b1a : (idx < 64) ? b1b : (idx < 96) ? b2a : b2b;
        bcat[idx] = b[idx & 31];
    }
    if (idx < 40) b3s[idx] = b3a[idx] + b3b[idx];
}

// ---------------- MFMA GEMM ----------------
// HWp layout: 4 slices s=0..3, each [N][32] bf16, where slice s pos = b*8 + (f&7)
// holds output col c = b*32 + s*8 + (f&7)  (b = conv block, f = feat within block).
// Value = bf16( (x@Wcat)[r][c] * dinv[r] ).
// Block: 64 rows x 128 cols, 4 waves; wave w = all 64 rows x cols [w*32, w*32+32).
// BK=64, A+B double-buffered in LDS (bf16, 16B-chunk XOR swizzle).

#define GBM 64

__global__ __launch_bounds__(256) void gemm_mfma(const float* __restrict__ X,
                                                 const ushort* __restrict__ Wt,
                                                 const float* __restrict__ dinv,
                                                 ushort* __restrict__ HWp, int N) {
    __shared__ ushort Alds[2][64 * 64];    // [buf][row][k] 16B chunks swz: c' = c ^ (row&7)
    __shared__ ushort Blds[2][128 * 64];
    const int tid = threadIdx.x;
    const int lane = tid & 63;
    const int wave = tid >> 6;
    const int rQ = lane & 15, g = lane >> 4;
    const int swz = rQ & 7;
    const int rowBase = blockIdx.x * GBM;

    // A staging: row ar (0..63), quarter aq; load i covers k = i*16 + aq*4 .. +4
    const int ar = tid >> 2, aq = tid & 3;
    int arow = rowBase + ar; if (arow > N - 1) arow = N - 1;
    const float* aglob = X + (size_t)arow * 512 + aq * 4;

    // B staging: wrow br (0..127), half bh; load i covers k = bh*32 + i*8 .. +8
    const int br = tid >> 1, bh = tid & 1;
    const ushort* bglob = Wt + (size_t)br * 512 + bh * 32;

    float4 a4[4];
    uint4 b4[4];
    f32x4 acc[4][2] = {};    // [rowTile rt][colTile ct2]

#define LOAD_REGS(k0)                                                       \
    {                                                                       \
        _Pragma("unroll")                                                   \
        for (int i = 0; i < 4; ++i) a4[i] = *(const float4*)(aglob + (k0) + i * 16); \
        _Pragma("unroll")                                                   \
        for (int i = 0; i < 4; ++i) b4[i] = *(const uint4*)(bglob + (k0) + i * 8);   \
    }

#define WRITE_LDS(buf)                                                      \
    {                                                                       \
        _Pragma("unroll")                                                   \
        for (int i = 0; i < 4; ++i) {                                       \
            int c = i * 2 + (aq >> 1);                                      \
            ushort4 u; u.x = f2bf(a4[i].x); u.y = f2bf(a4[i].y);            \
            u.z = f2bf(a4[i].z); u.w = f2bf(a4[i].w);                       \
            *(ushort4*)(&Alds[buf][ar * 64 + ((c ^ (ar & 7)) << 3) + (aq & 1) * 4]) = u; \
        }                                                                   \
        ushort* bp = &Blds[buf][br * 64];                                   \
        _Pragma("unroll")                                                   \
        for (int i = 0; i < 4; ++i) {                                       \
            int c = bh * 4 + i;                                             \
            *(uint4*)(bp + ((c ^ (br & 7)) << 3)) = b4[i];                  \
        }                                                                   \
    }

#define COMPUTE(buf)                                                        \
    {                                                                       \
        short8 bf[2][2];                                                    \
        _Pragma("unroll")                                                   \
        for (int ct2 = 0; ct2 < 2; ++ct2) {                                 \
            int brow = wave * 32 + ct2 * 16 + rQ;                           \
            _Pragma("unroll")                                               \
            for (int sub = 0; sub < 2; ++sub)                               \
                bf[ct2][sub] = *(const short8*)(&Blds[buf][brow * 64 + (((sub * 4 + g) ^ swz) << 3)]); \
        }                                                                   \
        _Pragma("unroll")                                                   \
        for (int rt = 0; rt < 4; ++rt) {                                    \
            int arw = rt * 16 + rQ;                                         \
            _Pragma("unroll")                                               \
            for (int sub = 0; sub < 2; ++sub) {                             \
                short8 af = *(const short8*)(&Alds[buf][arw * 64 + (((sub * 4 + g) ^ swz) << 3)]); \
                _Pragma("unroll")                                           \
                for (int ct2 = 0; ct2 < 2; ++ct2)                           \
                    acc[rt][ct2] = __builtin_amdgcn_mfma_f32_16x16x32_bf16( \
                        af, bf[ct2][sub], acc[rt][ct2], 0, 0, 0);           \
            }                                                               \
        }                                                                   \
    }

    LOAD_REGS(0);
    WRITE_LDS(0);
    for (int s = 0; s < 8; ++s) {
        __syncthreads();
        if (s + 1 < 8) LOAD_REGS((s + 1) * 64);
        COMPUTE(s & 1);
        if (s + 1 < 8) {
            __syncthreads();
            WRITE_LDS((s + 1) & 1);
        }
    }

    const size_t slice_stride = (size_t)N * 32;
    #pragma unroll
    for (int rt = 0; rt < 4; ++rt) {
        #pragma unroll
        for (int j = 0; j < 4; ++j) {
            int r = rowBase + rt * 16 + g * 4 + j;
            if (r < N) {
                float dv = dinv[r];
                #pragma unroll
                for (int ct2 = 0; ct2 < 2; ++ct2) {
                    int c = wave * 32 + ct2 * 16 + rQ;
                    int b = c >> 5, f = c & 31;
                    HWp[(size_t)(f >> 3) * slice_stride + (size_t)r * 32 + b * 8 + (f & 7)]
                        = f2bf(acc[rt][ct2][j] * dv);
                }
            }
        }
    }
#undef LOAD_REGS
#undef WRITE_LDS
#undef COMPUTE
}

// ---------------- aggregation 128, feature-sliced (4 slices, XCD-pinned) ----------------
// slice s: gather [N][32]bf16 region (6.4MB); lane l (8/node): block b=l>>1, feats s*8+(l&1)*4..+4
// xsp output: 2 regions [N][16] bf16 (pre-scaled by dinv[node]); slice s owns feats s*8..s*8+8.

__global__ __launch_bounds__(256) void agg128(const ushort* __restrict__ HWp, const float* __restrict__ dinv,
                                              const int* __restrict__ offs, const int* __restrict__ csr,
                                              const float* __restrict__ bcat, ushort* __restrict__ xsp, int N) {
    int s = blockIdx.x & 3;
    int nblk = blockIdx.x >> 2;
    int t = nblk * 256 + threadIdx.x;
    int node = t >> 3, l = t & 7;
    if (node >= N) return;
    const ushort4* H = (const ushort4*)(HWp + (size_t)s * N * 32);
    ushort4 h = H[(size_t)node * 8 + l];
    float a0 = bf2f(h.x), a1 = bf2f(h.y), a2 = bf2f(h.z), a3 = bf2f(h.w);
    int e1 = offs[node + 1];
    for (int j = offs[node]; j < e1; ++j) {
        int sv = csr[j];
        ushort4 v = H[(size_t)sv * 8 + l];
        a0 += bf2f(v.x); a1 += bf2f(v.y); a2 += bf2f(v.z); a3 += bf2f(v.w);
    }
    float di = dinv[node];
    int b = l >> 1, half = l & 1;
    float4 bv = *(const float4*)(bcat + b * 32 + s * 8 + half * 4);
    float r0 = fmaxf(di * a0 + bv.x, 0.f);
    float r1 = fmaxf(di * a1 + bv.y, 0.f);
    float r2 = fmaxf(di * a2 + bv.z, 0.f);
    float r3 = fmaxf(di * a3 + bv.w, 0.f);
    r0 += __shfl_xor(r0, 2); r1 += __shfl_xor(r1, 2); r2 += __shfl_xor(r2, 2); r3 += __shfl_xor(r3, 2);
    r0 += __shfl_xor(r0, 4); r1 += __shfl_xor(r1, 4); r2 += __shfl_xor(r2, 4); r3 += __shfl_xor(r3, 4);
    if (b == 0) {   // lanes l=0,1 hold block-sums for feats s*8 + half*4 ..
        ushort4 o;
        o.x = f2bf(r0 * di); o.y = f2bf(r1 * di); o.z = f2bf(r2 * di); o.w = f2bf(r3 * di);
        ushort* xr = xsp + (size_t)(s >> 1) * N * 16;
        *(ushort4*)(xr + (size_t)node * 16 + (s & 1) * 8 + half * 4) = o;
    }
}

// ---------------- aggregation 32, feature-sliced (2 slices, XCD-pinned) ----------------
// slice rs: gather [N][16]bf16 region (3.2MB, L2-resident); 4 lanes/node; axs f32 [N][32].

__global__ __launch_bounds__(256) void agg32(const ushort* __restrict__ xsp, const float* __restrict__ dinv,
                                             const int* __restrict__ offs, const int* __restrict__ csr,
                                             float* __restrict__ axs, int N) {
    int rs = blockIdx.x & 1;
    int nblk = blockIdx.x >> 1;
    int t = nblk * 256 + threadIdx.x;
    int node = t >> 2, l = t & 3;
    if (node >= N) return;
    const ushort4* Xr = (const ushort4*)(xsp + (size_t)rs * N * 16);
    ushort4 h = Xr[(size_t)node * 4 + l];
    float a0 = bf2f(h.x), a1 = bf2f(h.y), a2 = bf2f(h.z), a3 = bf2f(h.w);
    int e1 = offs[node + 1];
    for (int j = offs[node]; j < e1; ++j) {
        int sv = csr[j];
        ushort4 v = Xr[(size_t)sv * 4 + l];
        a0 += bf2f(v.x); a1 += bf2f(v.y); a2 += bf2f(v.z); a3 += bf2f(v.w);
    }
    float di = dinv[node];
    float4 o = make_float4(a0 * di, a1 * di, a2 * di, a3 * di);
    *(float4*)(axs + (size_t)node * 32 + rs * 16 + l * 4) = o;
}

// ---------------- final: logits = axs @ W3s + b3s ; log_softmax ----------------

__global__ __launch_bounds__(256) void final_kernel(const float* __restrict__ axs, const float* __restrict__ W3s,
                                                    const float* __restrict__ b3s, float* __restrict__ out, int N) {
    __shared__ float w[32 * 40];
    __shared__ float b[40];
    int tid = threadIdx.x;
    for (int i = tid; i < 1280; i += 256) w[i] = W3s[i];
    if (tid < 40) b[tid] = b3s[tid];
    __syncthreads();
    int i = blockIdx.x * 256 + tid;
    if (i >= N) return;
    float a[32];
    #pragma unroll
    for (int q = 0; q < 8; ++q) {
        float4 v = *(const float4*)(axs + (size_t)i * 32 + q * 4);
        a[q * 4] = v.x; a[q * 4 + 1] = v.y; a[q * 4 + 2] = v.z; a[q * 4 + 3] = v.w;
    }
    float acc[40];
    #pragma unroll
    for (int c = 0; c < 40; ++c) acc[c] = b[c];
    #pragma unroll
    for (int k = 0; k < 32; ++k) {
        float av = a[k];
        #pragma unroll
        for (int c = 0; c < 40; ++c) acc[c] += av * w[k * 40 + c];
    }
    float m = acc[0];
    #pragma unroll
    for (int c = 1; c < 40; ++c) m = fmaxf(m, acc[c]);
    float sum = 0.f;
    #pragma unroll
    for (int c = 0; c < 40; ++c) sum += expf(acc[c] - m);
    float lg = m + logf(sum);
    #pragma unroll
    for (int c = 0; c < 40; ++c) out[(size_t)i * 40 + c] = acc[c] - lg;
}

// ---------------- launch ----------------

extern "C" void kernel_launch(void* const* d_in, const int* in_sizes, int n_in,
                              void* d_out, int out_size, void* d_ws, size_t ws_size,
                              hipStream_t stream) {
    const float* x   = (const float*)d_in[0];
    const int*   ei  = (const int*)d_in[1];
    const float* W1a = (const float*)d_in[2];  const float* b1a = (const float*)d_in[3];
    const float* W1b = (const float*)d_in[4];  const float* b1b = (const float*)d_in[5];
    const float* W2a = (const float*)d_in[6];  const float* b2a = (const float*)d_in[7];
    const float* W2b = (const float*)d_in[8];  const float* b2b = (const float*)d_in[9];
    const float* W3a = (const float*)d_in[10]; const float* b3a = (const float*)d_in[11];
    const float* W3b = (const float*)d_in[12]; const float* b3b = (const float*)d_in[13];

    int N = in_sizes[0] / 512;
    int E = in_sizes[1] / 2;
    const int* srcv = ei;
    const int* dstv = ei + E;

    char* ws = (char*)d_ws;
    size_t off = 0;
    auto alloc = [&](size_t bytes) { void* p = ws + off; off = (off + bytes + 255) & ~(size_t)255; return p; };
    int*    cnt    = (int*)   alloc((size_t)N * 4);
    int*    cursor = (int*)   alloc((size_t)N * 4);
    int*    offs   = (int*)   alloc((size_t)(N + 1) * 4);
    float*  dinv   = (float*) alloc((size_t)N * 4);
    int*    csr    = (int*)   alloc((size_t)E * 4);
    ushort* Wt     = (ushort*)alloc(128 * 512 * 2);
    float*  bcat   = (float*) alloc(128 * 4);
    float*  W3s    = (float*) alloc(1280 * 4);
    float*  b3s    = (float*) alloc(40 * 4);
    ushort* HWp    = (ushort*)alloc((size_t)N * 128 * 2);   // 4 slices x [N][32] bf16
    ushort* xsp    = (ushort*)alloc((size_t)N * 32 * 2);    // 2 regions x [N][16] bf16
    float*  axs    = (float*) alloc((size_t)N * 32 * 4);

    hipMemsetAsync(cnt, 0, (size_t)N * 4, stream);
    hipMemsetAsync(cursor, 0, (size_t)N * 4, stream);

    count_kernel<<<2048, 256, 0, stream>>>(dstv, cnt, E);
    dinv_kernel<<<(N + 255) / 256, 256, 0, stream>>>(cnt, dinv, N);
    scan_kernel<<<1, 1024, 0, stream>>>(cnt, offs, N);
    scatter_kernel<<<2048, 256, 0, stream>>>(srcv, dstv, offs, cursor, csr, E);
    prep_kernel<<<256, 256, 0, stream>>>(W1a, W1b, W2a, W2b, b1a, b1b, b2a, b2b,
                                         W3a, W3b, b3a, b3b, Wt, bcat, W3s, b3s);
    gemm_mfma<<<(N + GBM - 1) / GBM, 256, 0, stream>>>(x, Wt, dinv, HWp, N);
    {
        int nodeblk = (N * 8 + 255) / 256;       // 32 nodes / block
        agg128<<<nodeblk * 4, 256, 0, stream>>>(HWp, dinv, offs, csr, bcat, xsp, N);
    }
    {
        int nodeblk = (N * 4 + 255) / 256;       // 64 nodes / block
        agg32<<<nodeblk * 2, 256, 0, stream>>>(xsp, dinv, offs, csr, axs, N);
    }
    final_kernel<<<(N + 255) / 256, 256, 0, stream>>>(axs, W3s, b3s, (float*)d_out, N);
}

// Round 4
// 730.864 us; speedup vs baseline: 1.1859x; 1.1859x over previous
//
#include <hip/hip_runtime.h>
#include <hip/hip_bf16.h>
#include <math.h>

typedef __attribute__((ext_vector_type(8))) short short8;
typedef __attribute__((ext_vector_type(4))) float f32x4;

__device__ inline ushort f2bf(float f) {
    uint u = __builtin_bit_cast(uint, f);
    u += 0x7fffu + ((u >> 16) & 1u);          // round-to-nearest-even
    return (ushort)(u >> 16);
}
__device__ inline float bf2f(ushort h) {
    return __builtin_bit_cast(float, (uint)h << 16);
}

// ---------------- degree / CSR build ----------------

__global__ __launch_bounds__(256) void count_kernel(const int* __restrict__ dst, int* __restrict__ cnt, int E) {
    for (int e = blockIdx.x * blockDim.x + threadIdx.x; e < E; e += gridDim.x * blockDim.x)
        atomicAdd(&cnt[dst[e]], 1);
}

__global__ __launch_bounds__(256) void dinv_kernel(const int* __restrict__ cnt, float* __restrict__ dinv, int N) {
    int i = blockIdx.x * 256 + threadIdx.x;
    if (i < N) dinv[i] = rsqrtf((float)(cnt[i] + 1));   // +1 self loop; deg >= 1 always
}

__global__ __launch_bounds__(1024) void scan_kernel(const int* __restrict__ cnt, int* __restrict__ offs, int N) {
    __shared__ int part[1024];
    int tid = threadIdx.x;
    int chunk = (N + 1023) / 1024;
    int beg = tid * chunk;
    int end = beg + chunk; if (end > N) end = N;
    int s = 0;
    for (int i = beg; i < end; ++i) s += cnt[i];
    part[tid] = s;
    __syncthreads();
    for (int off = 1; off < 1024; off <<= 1) {
        int t = (tid >= off) ? part[tid - off] : 0;
        __syncthreads();
        part[tid] += t;
        __syncthreads();
    }
    int run = (tid > 0) ? part[tid - 1] : 0;
    for (int i = beg; i < end; ++i) { offs[i] = run; run += cnt[i]; }
    if (beg < N && end == N) offs[N] = run;
}

__global__ __launch_bounds__(256) void scatter_kernel(const int* __restrict__ src, const int* __restrict__ dst,
                                                      const int* __restrict__ offs, int* __restrict__ cursor,
                                                      int* __restrict__ csr, int E) {
    for (int e = blockIdx.x * blockDim.x + threadIdx.x; e < E; e += gridDim.x * blockDim.x) {
        int d = dst[e];
        int p = atomicAdd(&cursor[d], 1);
        csr[offs[d] + p] = src[e];
    }
}

// ---------------- weight prep: Wt[128][512] bf16 (transposed), bcat[128], W3s[32*40], b3s[40] ----

__global__ __launch_bounds__(256) void prep_kernel(const float* __restrict__ W1a, const float* __restrict__ W1b,
                                                   const float* __restrict__ W2a, const float* __restrict__ W2b,
                                                   const float* __restrict__ b1a, const float* __restrict__ b1b,
                                                   const float* __restrict__ b2a, const float* __restrict__ b2b,
                                                   const float* __restrict__ W3a, const float* __restrict__ W3b,
                                                   const float* __restrict__ b3a, const float* __restrict__ b3b,
                                                   ushort* __restrict__ Wt, float* __restrict__ bcat,
                                                   float* __restrict__ W3s, float* __restrict__ b3s) {
    int idx = blockIdx.x * 256 + threadIdx.x;
    if (idx < 128 * 512) {
        int c = idx >> 9, k = idx & 511;   // Wt[c][k] = Wcat[k][c]
        const float* W = (c < 32) ? W1a : (c < 64) ? W1b : (c < 96) ? W2a : W2b;
        Wt[idx] = f2bf(W[k * 32 + (c & 31)]);
    }
    if (idx < 1280) W3s[idx] = W3a[idx] + W3b[idx];
    if (idx < 128) {
        const float* b = (idx < 32) ? b1a : (idx < 64) ? b1b : (idx < 96) ? b2a : b2b;
        bcat[idx] = b[idx & 31];
    }
    if (idx < 40) b3s[idx] = b3a[idx] + b3b[idx];
}

// ---------------- MFMA GEMM: HWp[N][128] = bf16( (X@Wcat)[r][c] * dinv[r] ) ----------------
// Block: 64 rows x 128 cols, 4 waves; wave w = all 64 rows x cols [w*32, w*32+32).
// BK=64, A+B double-buffered in LDS (bf16, 16B-chunk XOR swizzle).

#define GBM 64

__global__ __launch_bounds__(256) void gemm_mfma(const float* __restrict__ X,
                                                 const ushort* __restrict__ Wt,
                                                 const float* __restrict__ dinv,
                                                 ushort* __restrict__ HWp, int N) {
    __shared__ ushort Alds[2][64 * 64];    // [buf][row][k] 16B chunks swz: c' = c ^ (row&7)
    __shared__ ushort Blds[2][128 * 64];
    const int tid = threadIdx.x;
    const int lane = tid & 63;
    const int wave = tid >> 6;
    const int rQ = lane & 15, g = lane >> 4;
    const int swz = rQ & 7;
    const int rowBase = blockIdx.x * GBM;

    // A staging: row ar (0..63), quarter aq; load i covers k = i*16 + aq*4 .. +4
    const int ar = tid >> 2, aq = tid & 3;
    int arow = rowBase + ar; if (arow > N - 1) arow = N - 1;
    const float* aglob = X + (size_t)arow * 512 + aq * 4;

    // B staging: wrow br (0..127), half bh; load i covers k = bh*32 + i*8 .. +8
    const int br = tid >> 1, bh = tid & 1;
    const ushort* bglob = Wt + (size_t)br * 512 + bh * 32;

    float4 a4[4];
    uint4 b4[4];
    f32x4 acc[4][2] = {};    // [rowTile rt][colTile ct2]

#define LOAD_REGS(k0)                                                       \
    {                                                                       \
        _Pragma("unroll")                                                   \
        for (int i = 0; i < 4; ++i) a4[i] = *(const float4*)(aglob + (k0) + i * 16); \
        _Pragma("unroll")                                                   \
        for (int i = 0; i < 4; ++i) b4[i] = *(const uint4*)(bglob + (k0) + i * 8);   \
    }

#define WRITE_LDS(buf)                                                      \
    {                                                                       \
        _Pragma("unroll")                                                   \
        for (int i = 0; i < 4; ++i) {                                       \
            int c = i * 2 + (aq >> 1);                                      \
            ushort4 u; u.x = f2bf(a4[i].x); u.y = f2bf(a4[i].y);            \
            u.z = f2bf(a4[i].z); u.w = f2bf(a4[i].w);                       \
            *(ushort4*)(&Alds[buf][ar * 64 + ((c ^ (ar & 7)) << 3) + (aq & 1) * 4]) = u; \
        }                                                                   \
        ushort* bp = &Blds[buf][br * 64];                                   \
        _Pragma("unroll")                                                   \
        for (int i = 0; i < 4; ++i) {                                       \
            int c = bh * 4 + i;                                             \
            *(uint4*)(bp + ((c ^ (br & 7)) << 3)) = b4[i];                  \
        }                                                                   \
    }

#define COMPUTE(buf)                                                        \
    {                                                                       \
        short8 bf[2][2];                                                    \
        _Pragma("unroll")                                                   \
        for (int ct2 = 0; ct2 < 2; ++ct2) {                                 \
            int brow = wave * 32 + ct2 * 16 + rQ;                           \
            _Pragma("unroll")                                               \
            for (int sub = 0; sub < 2; ++sub)                               \
                bf[ct2][sub] = *(const short8*)(&Blds[buf][brow * 64 + (((sub * 4 + g) ^ swz) << 3)]); \
        }                                                                   \
        _Pragma("unroll")                                                   \
        for (int rt = 0; rt < 4; ++rt) {                                    \
            int arw = rt * 16 + rQ;                                         \
            _Pragma("unroll")                                               \
            for (int sub = 0; sub < 2; ++sub) {                             \
                short8 af = *(const short8*)(&Alds[buf][arw * 64 + (((sub * 4 + g) ^ swz) << 3)]); \
                _Pragma("unroll")                                           \
                for (int ct2 = 0; ct2 < 2; ++ct2)                           \
                    acc[rt][ct2] = __builtin_amdgcn_mfma_f32_16x16x32_bf16( \
                        af, bf[ct2][sub], acc[rt][ct2], 0, 0, 0);           \
            }                                                               \
        }                                                                   \
    }

    LOAD_REGS(0);
    WRITE_LDS(0);
    for (int s = 0; s < 8; ++s) {
        __syncthreads();
        if (s + 1 < 8) LOAD_REGS((s + 1) * 64);
        COMPUTE(s & 1);
        if (s + 1 < 8) {
            __syncthreads();
            WRITE_LDS((s + 1) & 1);
        }
    }

    // epilogue: scale by dinv[row], store bf16 monolithic [N][128]
    #pragma unroll
    for (int rt = 0; rt < 4; ++rt) {
        #pragma unroll
        for (int j = 0; j < 4; ++j) {
            int r = rowBase + rt * 16 + g * 4 + j;
            if (r < N) {
                float dv = dinv[r];
                #pragma unroll
                for (int ct2 = 0; ct2 < 2; ++ct2) {
                    int c = wave * 32 + ct2 * 16 + rQ;
                    HWp[(size_t)r * 128 + c] = f2bf(acc[rt][ct2][j] * dv);
                }
            }
        }
    }
#undef LOAD_REGS
#undef WRITE_LDS
#undef COMPUTE
}

// ---------------- aggregation 128 (bf16 gather, unroll-4 MLP) + fused relu/bias/block-sum ----------
// HWp pre-scaled by dinv[src]. xsp[node][q] = bf16( dinv[node] * sum_blk relu(dinv[node]*agg + bcat) )

__global__ __launch_bounds__(256) void agg128(const ushort* __restrict__ HWp, const float* __restrict__ dinv,
                                              const int* __restrict__ offs, const int* __restrict__ csr,
                                              const float* __restrict__ bcat, ushort* __restrict__ xsp, int N) {
    int t = blockIdx.x * 256 + threadIdx.x;
    int node = t >> 5, c = t & 31;      // lane c holds features 4c..4c+3
    if (node >= N) return;
    const ushort4* H = (const ushort4*)HWp;
    ushort4 h = H[(size_t)node * 32 + c];
    float a0 = bf2f(h.x), a1 = bf2f(h.y), a2 = bf2f(h.z), a3 = bf2f(h.w);
    int j = offs[node];
    int e1 = offs[node + 1];
    int jend = j + ((e1 - j) & ~3);
    for (; j < jend; j += 4) {
        int s0 = csr[j], s1 = csr[j + 1], s2 = csr[j + 2], s3 = csr[j + 3];
        ushort4 v0 = H[(size_t)s0 * 32 + c];
        ushort4 v1 = H[(size_t)s1 * 32 + c];
        ushort4 v2 = H[(size_t)s2 * 32 + c];
        ushort4 v3 = H[(size_t)s3 * 32 + c];
        a0 += bf2f(v0.x) + bf2f(v1.x) + bf2f(v2.x) + bf2f(v3.x);
        a1 += bf2f(v0.y) + bf2f(v1.y) + bf2f(v2.y) + bf2f(v3.y);
        a2 += bf2f(v0.z) + bf2f(v1.z) + bf2f(v2.z) + bf2f(v3.z);
        a3 += bf2f(v0.w) + bf2f(v1.w) + bf2f(v2.w) + bf2f(v3.w);
    }
    for (; j < e1; ++j) {
        int s = csr[j];
        ushort4 v = H[(size_t)s * 32 + c];
        a0 += bf2f(v.x); a1 += bf2f(v.y); a2 += bf2f(v.z); a3 += bf2f(v.w);
    }
    float di = dinv[node];
    float4 b = *(const float4*)(bcat + c * 4);
    float r0 = fmaxf(di * a0 + b.x, 0.f);
    float r1 = fmaxf(di * a1 + b.y, 0.f);
    float r2 = fmaxf(di * a2 + b.z, 0.f);
    float r3 = fmaxf(di * a3 + b.w, 0.f);
    r0 += __shfl_xor(r0, 8);  r1 += __shfl_xor(r1, 8);  r2 += __shfl_xor(r2, 8);  r3 += __shfl_xor(r3, 8);
    r0 += __shfl_xor(r0, 16); r1 += __shfl_xor(r1, 16); r2 += __shfl_xor(r2, 16); r3 += __shfl_xor(r3, 16);
    if ((c & 24) == 0) {   // lanes c=0..7 hold block-sums for feats 4c..4c+3
        ushort4 o;
        o.x = f2bf(r0 * di); o.y = f2bf(r1 * di); o.z = f2bf(r2 * di); o.w = f2bf(r3 * di);
        *(ushort4*)(xsp + (size_t)node * 32 + c * 4) = o;
    }
}

// ---------------- aggregation 32 (bf16 gather, unroll-4 MLP) -> axs f32 ----------------
// xsp pre-scaled by dinv[src]; 4 lanes/node, 16B loads (8 feats each).

__global__ __launch_bounds__(256) void agg32(const ushort* __restrict__ xsp, const float* __restrict__ dinv,
                                             const int* __restrict__ offs, const int* __restrict__ csr,
                                             float* __restrict__ axs, int N) {
    int t = blockIdx.x * 256 + threadIdx.x;
    int node = t >> 2, l = t & 3;
    if (node >= N) return;
    const short8* Xr = (const short8*)xsp;   // [N][4] chunks of 8 bf16
    short8 h = Xr[(size_t)node * 4 + l];
    float a[8];
    #pragma unroll
    for (int i = 0; i < 8; ++i) a[i] = bf2f((ushort)h[i]);
    int j = offs[node];
    int e1 = offs[node + 1];
    int jend = j + ((e1 - j) & ~3);
    for (; j < jend; j += 4) {
        int s0 = csr[j], s1 = csr[j + 1], s2 = csr[j + 2], s3 = csr[j + 3];
        short8 v0 = Xr[(size_t)s0 * 4 + l];
        short8 v1 = Xr[(size_t)s1 * 4 + l];
        short8 v2 = Xr[(size_t)s2 * 4 + l];
        short8 v3 = Xr[(size_t)s3 * 4 + l];
        #pragma unroll
        for (int i = 0; i < 8; ++i)
            a[i] += bf2f((ushort)v0[i]) + bf2f((ushort)v1[i]) + bf2f((ushort)v2[i]) + bf2f((ushort)v3[i]);
    }
    for (; j < e1; ++j) {
        int s = csr[j];
        short8 v = Xr[(size_t)s * 4 + l];
        #pragma unroll
        for (int i = 0; i < 8; ++i) a[i] += bf2f((ushort)v[i]);
    }
    float di = dinv[node];
    float4 o0 = make_float4(a[0] * di, a[1] * di, a[2] * di, a[3] * di);
    float4 o1 = make_float4(a[4] * di, a[5] * di, a[6] * di, a[7] * di);
    float* dst = axs + (size_t)node * 32 + l * 8;
    *(float4*)dst = o0;
    *(float4*)(dst + 4) = o1;
}

// ---------------- final: logits = axs @ W3s + b3s ; log_softmax ----------------

__global__ __launch_bounds__(256) void final_kernel(const float* __restrict__ axs, const float* __restrict__ W3s,
                                                    const float* __restrict__ b3s, float* __restrict__ out, int N) {
    __shared__ float w[32 * 40];
    __shared__ float b[40];
    int tid = threadIdx.x;
    for (int i = tid; i < 1280; i += 256) w[i] = W3s[i];
    if (tid < 40) b[tid] = b3s[tid];
    __syncthreads();
    int i = blockIdx.x * 256 + tid;
    if (i >= N) return;
    float a[32];
    #pragma unroll
    for (int q = 0; q < 8; ++q) {
        float4 v = *(const float4*)(axs + (size_t)i * 32 + q * 4);
        a[q * 4] = v.x; a[q * 4 + 1] = v.y; a[q * 4 + 2] = v.z; a[q * 4 + 3] = v.w;
    }
    float acc[40];
    #pragma unroll
    for (int c = 0; c < 40; ++c) acc[c] = b[c];
    #pragma unroll
    for (int k = 0; k < 32; ++k) {
        float av = a[k];
        #pragma unroll
        for (int c = 0; c < 40; ++c) acc[c] += av * w[k * 40 + c];
    }
    float m = acc[0];
    #pragma unroll
    for (int c = 1; c < 40; ++c) m = fmaxf(m, acc[c]);
    float sum = 0.f;
    #pragma unroll
    for (int c = 0; c < 40; ++c) sum += expf(acc[c] - m);
    float lg = m + logf(sum);
    #pragma unroll
    for (int c = 0; c < 40; ++c) out[(size_t)i * 40 + c] = acc[c] - lg;
}

// ---------------- launch ----------------

extern "C" void kernel_launch(void* const* d_in, const int* in_sizes, int n_in,
                              void* d_out, int out_size, void* d_ws, size_t ws_size,
                              hipStream_t stream) {
    const float* x   = (const float*)d_in[0];
    const int*   ei  = (const int*)d_in[1];
    const float* W1a = (const float*)d_in[2];  const float* b1a = (const float*)d_in[3];
    const float* W1b = (const float*)d_in[4];  const float* b1b = (const float*)d_in[5];
    const float* W2a = (const float*)d_in[6];  const float* b2a = (const float*)d_in[7];
    const float* W2b = (const float*)d_in[8];  const float* b2b = (const float*)d_in[9];
    const float* W3a = (const float*)d_in[10]; const float* b3a = (const float*)d_in[11];
    const float* W3b = (const float*)d_in[12]; const float* b3b = (const float*)d_in[13];

    int N = in_sizes[0] / 512;
    int E = in_sizes[1] / 2;
    const int* srcv = ei;
    const int* dstv = ei + E;

    char* ws = (char*)d_ws;
    size_t off = 0;
    auto alloc = [&](size_t bytes) { void* p = ws + off; off = (off + bytes + 255) & ~(size_t)255; return p; };
    int*    cnt    = (int*)   alloc((size_t)N * 4);
    int*    cursor = (int*)   alloc((size_t)N * 4);
    int*    offs   = (int*)   alloc((size_t)(N + 1) * 4);
    float*  dinv   = (float*) alloc((size_t)N * 4);
    int*    csr    = (int*)   alloc((size_t)E * 4);
    ushort* Wt     = (ushort*)alloc(128 * 512 * 2);
    float*  bcat   = (float*) alloc(128 * 4);
    float*  W3s    = (float*) alloc(1280 * 4);
    float*  b3s    = (float*) alloc(40 * 4);
    ushort* HWp    = (ushort*)alloc((size_t)N * 128 * 2);   // [N][128] bf16
    ushort* xsp    = (ushort*)alloc((size_t)N * 32 * 2);    // [N][32] bf16
    float*  axs    = (float*) alloc((size_t)N * 32 * 4);

    hipMemsetAsync(cnt, 0, (size_t)N * 4, stream);
    hipMemsetAsync(cursor, 0, (size_t)N * 4, stream);

    count_kernel<<<2048, 256, 0, stream>>>(dstv, cnt, E);
    dinv_kernel<<<(N + 255) / 256, 256, 0, stream>>>(cnt, dinv, N);
    scan_kernel<<<1, 1024, 0, stream>>>(cnt, offs, N);
    scatter_kernel<<<2048, 256, 0, stream>>>(srcv, dstv, offs, cursor, csr, E);
    prep_kernel<<<256, 256, 0, stream>>>(W1a, W1b, W2a, W2b, b1a, b1b, b2a, b2b,
                                         W3a, W3b, b3a, b3b, Wt, bcat, W3s, b3s);
    gemm_mfma<<<(N + GBM - 1) / GBM, 256, 0, stream>>>(x, Wt, dinv, HWp, N);
    agg128<<<((size_t)N * 32 + 255) / 256, 256, 0, stream>>>(HWp, dinv, offs, csr, bcat, xsp, N);
    agg32<<<((size_t)N * 4 + 255) / 256, 256, 0, stream>>>(xsp, dinv, offs, csr, axs, N);
    final_kernel<<<(N + 255) / 256, 256, 0, stream>>>(axs, W3s, b3s, (float*)d_out, N);
}

// Round 5
// 619.284 us; speedup vs baseline: 1.3996x; 1.1802x over previous
//
#include <hip/hip_runtime.h>
#include <hip/hip_bf16.h>
#include <math.h>

typedef __attribute__((ext_vector_type(8))) short short8;
typedef __attribute__((ext_vector_type(4))) float f32x4;

__device__ inline ushort f2bf(float f) {
    uint u = __builtin_bit_cast(uint, f);
    u += 0x7fffu + ((u >> 16) & 1u);          // round-to-nearest-even
    return (ushort)(u >> 16);
}
__device__ inline float bf2f(ushort h) {
    return __builtin_bit_cast(float, (uint)h << 16);
}

// ---------------- degree / CSR build ----------------

__global__ __launch_bounds__(256) void count_kernel(const int* __restrict__ dst, int* __restrict__ cnt, int E) {
    int t = blockIdx.x * blockDim.x + threadIdx.x;
    int stride = gridDim.x * blockDim.x;
    int E4 = E >> 2;
    const int4* d4 = (const int4*)dst;
    for (int e = t; e < E4; e += stride) {
        int4 v = d4[e];
        atomicAdd(&cnt[v.x], 1);
        atomicAdd(&cnt[v.y], 1);
        atomicAdd(&cnt[v.z], 1);
        atomicAdd(&cnt[v.w], 1);
    }
    for (int e = E4 * 4 + t; e < E; e += stride)
        atomicAdd(&cnt[dst[e]], 1);
}

__global__ __launch_bounds__(256) void dinv_kernel(const int* __restrict__ cnt, float* __restrict__ dinv, int N) {
    int i = blockIdx.x * 256 + threadIdx.x;
    if (i < N) dinv[i] = rsqrtf((float)(cnt[i] + 1));   // +1 self loop; deg >= 1 always
}

__global__ __launch_bounds__(1024) void scan_kernel(const int* __restrict__ cnt, int* __restrict__ offs, int N) {
    __shared__ int part[1024];
    int tid = threadIdx.x;
    int chunk = (((N + 1023) >> 10) + 3) & ~3;      // multiple of 4 -> aligned int4
    int beg = tid * chunk;
    int end = beg + chunk; if (end > N) end = N;
    int s = 0;
    int i = beg;
    for (; i + 3 < end; i += 4) {
        int4 v = *(const int4*)(cnt + i);
        s += v.x + v.y + v.z + v.w;
    }
    for (; i < end; ++i) s += cnt[i];
    part[tid] = s;
    __syncthreads();
    for (int off = 1; off < 1024; off <<= 1) {
        int t = (tid >= off) ? part[tid - off] : 0;
        __syncthreads();
        part[tid] += t;
        __syncthreads();
    }
    int run = (tid > 0) ? part[tid - 1] : 0;
    i = beg;
    for (; i + 3 < end; i += 4) {
        int4 v = *(const int4*)(cnt + i);
        offs[i] = run; run += v.x;
        offs[i + 1] = run; run += v.y;
        offs[i + 2] = run; run += v.z;
        offs[i + 3] = run; run += v.w;
    }
    for (; i < end; ++i) { offs[i] = run; run += cnt[i]; }
    if (beg < N && end == N) offs[N] = run;
}

// XCD-range-partitioned scatter: group g = blockIdx&7 owns dst range [g*N/8,(g+1)*N/8).
// Each group's csr region (~1.6MB) stays resident in one XCD's L2 -> full-line write-backs.
__global__ __launch_bounds__(256) void scatter_kernel(const int* __restrict__ src, const int* __restrict__ dst,
                                                      const int* __restrict__ offs, int* __restrict__ cursor,
                                                      int* __restrict__ csr, int E, int N) {
    int grp = blockIdx.x & 7;
    int lo = (int)(((long long)N * grp) >> 3);
    int hi = (int)(((long long)N * (grp + 1)) >> 3);
    int nb = gridDim.x >> 3;
    int gb = blockIdx.x >> 3;
    for (int e = gb * blockDim.x + threadIdx.x; e < E; e += nb * blockDim.x) {
        int d = dst[e];
        if (d >= lo && d < hi) {
            int p = atomicAdd(&cursor[d], 1);
            csr[offs[d] + p] = src[e];
        }
    }
}

// ---------------- weight prep: Wt[128][512] bf16 (transposed), bcat[128], W3s[32*40], b3s[40] ----

__global__ __launch_bounds__(256) void prep_kernel(const float* __restrict__ W1a, const float* __restrict__ W1b,
                                                   const float* __restrict__ W2a, const float* __restrict__ W2b,
                                                   const float* __restrict__ b1a, const float* __restrict__ b1b,
                                                   const float* __restrict__ b2a, const float* __restrict__ b2b,
                                                   const float* __restrict__ W3a, const float* __restrict__ W3b,
                                                   const float* __restrict__ b3a, const float* __restrict__ b3b,
                                                   ushort* __restrict__ Wt, float* __restrict__ bcat,
                                                   float* __restrict__ W3s, float* __restrict__ b3s) {
    int idx = blockIdx.x * 256 + threadIdx.x;
    if (idx < 128 * 512) {
        int c = idx >> 9, k = idx & 511;   // Wt[c][k] = Wcat[k][c]
        const float* W = (c < 32) ? W1a : (c < 64) ? W1b : (c < 96) ? W2a : W2b;
        Wt[idx] = f2bf(W[k * 32 + (c & 31)]);
    }
    if (idx < 1280) W3s[idx] = W3a[idx] + W3b[idx];
    if (idx < 128) {
        const float* b = (idx < 32) ? b1a : (idx < 64) ? b1b : (idx < 96) ? b2a : b2b;
        bcat[idx] = b[idx & 31];
    }
    if (idx < 40) b3s[idx] = b3a[idx] + b3b[idx];
}

// ---------------- MFMA GEMM: HWp[N][128] = bf16( (X@Wcat)[r][c] * dinv[r] ) ----------------
// Block: 64 rows x 128 cols, 4 waves; wave w = all 64 rows x cols [w*32, w*32+32).
// BK=64, A+B double-buffered in LDS (bf16, 16B-chunk XOR swizzle).

#define GBM 64

__global__ __launch_bounds__(256) void gemm_mfma(const float* __restrict__ X,
                                                 const ushort* __restrict__ Wt,
                                                 const float* __restrict__ dinv,
                                                 ushort* __restrict__ HWp, int N) {
    __shared__ ushort Alds[2][64 * 64];    // [buf][row][k] 16B chunks swz: c' = c ^ (row&7)
    __shared__ ushort Blds[2][128 * 64];
    const int tid = threadIdx.x;
    const int lane = tid & 63;
    const int wave = tid >> 6;
    const int rQ = lane & 15, g = lane >> 4;
    const int swz = rQ & 7;
    const int rowBase = blockIdx.x * GBM;

    // A staging: row ar (0..63), quarter aq; load i covers k = i*16 + aq*4 .. +4
    const int ar = tid >> 2, aq = tid & 3;
    int arow = rowBase + ar; if (arow > N - 1) arow = N - 1;
    const float* aglob = X + (size_t)arow * 512 + aq * 4;

    // B staging: wrow br (0..127), half bh; load i covers k = bh*32 + i*8 .. +8
    const int br = tid >> 1, bh = tid & 1;
    const ushort* bglob = Wt + (size_t)br * 512 + bh * 32;

    float4 a4[4];
    uint4 b4[4];
    f32x4 acc[4][2] = {};    // [rowTile rt][colTile ct2]

#define LOAD_REGS(k0)                                                       \
    {                                                                       \
        _Pragma("unroll")                                                   \
        for (int i = 0; i < 4; ++i) a4[i] = *(const float4*)(aglob + (k0) + i * 16); \
        _Pragma("unroll")                                                   \
        for (int i = 0; i < 4; ++i) b4[i] = *(const uint4*)(bglob + (k0) + i * 8);   \
    }

#define WRITE_LDS(buf)                                                      \
    {                                                                       \
        _Pragma("unroll")                                                   \
        for (int i = 0; i < 4; ++i) {                                       \
            int c = i * 2 + (aq >> 1);                                      \
            ushort4 u; u.x = f2bf(a4[i].x); u.y = f2bf(a4[i].y);            \
            u.z = f2bf(a4[i].z); u.w = f2bf(a4[i].w);                       \
            *(ushort4*)(&Alds[buf][ar * 64 + ((c ^ (ar & 7)) << 3) + (aq & 1) * 4]) = u; \
        }                                                                   \
        ushort* bp = &Blds[buf][br * 64];                                   \
        _Pragma("unroll")                                                   \
        for (int i = 0; i < 4; ++i) {                                       \
            int c = bh * 4 + i;                                             \
            *(uint4*)(bp + ((c ^ (br & 7)) << 3)) = b4[i];                  \
        }                                                                   \
    }

#define COMPUTE(buf)                                                        \
    {                                                                       \
        short8 bf[2][2];                                                    \
        _Pragma("unroll")                                                   \
        for (int ct2 = 0; ct2 < 2; ++ct2) {                                 \
            int brow = wave * 32 + ct2 * 16 + rQ;                           \
            _Pragma("unroll")                                               \
            for (int sub = 0; sub < 2; ++sub)                               \
                bf[ct2][sub] = *(const short8*)(&Blds[buf][brow * 64 + (((sub * 4 + g) ^ swz) << 3)]); \
        }                                                                   \
        _Pragma("unroll")                                                   \
        for (int rt = 0; rt < 4; ++rt) {                                    \
            int arw = rt * 16 + rQ;                                         \
            _Pragma("unroll")                                               \
            for (int sub = 0; sub < 2; ++sub) {                             \
                short8 af = *(const short8*)(&Alds[buf][arw * 64 + (((sub * 4 + g) ^ swz) << 3)]); \
                _Pragma("unroll")                                           \
                for (int ct2 = 0; ct2 < 2; ++ct2)                           \
                    acc[rt][ct2] = __builtin_amdgcn_mfma_f32_16x16x32_bf16( \
                        af, bf[ct2][sub], acc[rt][ct2], 0, 0, 0);           \
            }                                                               \
        }                                                                   \
    }

    LOAD_REGS(0);
    WRITE_LDS(0);
    for (int s = 0; s < 8; ++s) {
        __syncthreads();
        if (s + 1 < 8) LOAD_REGS((s + 1) * 64);
        COMPUTE(s & 1);
        if (s + 1 < 8) {
            __syncthreads();
            WRITE_LDS((s + 1) & 1);
        }
    }

    // epilogue: scale by dinv[row], store bf16 monolithic [N][128]
    #pragma unroll
    for (int rt = 0; rt < 4; ++rt) {
        #pragma unroll
        for (int j = 0; j < 4; ++j) {
            int r = rowBase + rt * 16 + g * 4 + j;
            if (r < N) {
                float dv = dinv[r];
                #pragma unroll
                for (int ct2 = 0; ct2 < 2; ++ct2) {
                    int c = wave * 32 + ct2 * 16 + rQ;
                    HWp[(size_t)r * 128 + c] = f2bf(acc[rt][ct2][j] * dv);
                }
            }
        }
    }
#undef LOAD_REGS
#undef WRITE_LDS
#undef COMPUTE
}

// ---------------- aggregation 128 (bf16 gather, unroll-4 MLP) + fused relu/bias/block-sum ----------
// HWp pre-scaled by dinv[src]. xsp[node][q] = bf16( dinv[node] * sum_blk relu(dinv[node]*agg + bcat) )

__global__ __launch_bounds__(256) void agg128(const ushort* __restrict__ HWp, const float* __restrict__ dinv,
                                              const int* __restrict__ offs, const int* __restrict__ csr,
                                              const float* __restrict__ bcat, ushort* __restrict__ xsp, int N) {
    int t = blockIdx.x * 256 + threadIdx.x;
    int node = t >> 5, c = t & 31;      // lane c holds features 4c..4c+3
    if (node >= N) return;
    const ushort4* H = (const ushort4*)HWp;
    ushort4 h = H[(size_t)node * 32 + c];
    float a0 = bf2f(h.x), a1 = bf2f(h.y), a2 = bf2f(h.z), a3 = bf2f(h.w);
    int j = offs[node];
    int e1 = offs[node + 1];
    int jend = j + ((e1 - j) & ~3);
    for (; j < jend; j += 4) {
        int s0 = csr[j], s1 = csr[j + 1], s2 = csr[j + 2], s3 = csr[j + 3];
        ushort4 v0 = H[(size_t)s0 * 32 + c];
        ushort4 v1 = H[(size_t)s1 * 32 + c];
        ushort4 v2 = H[(size_t)s2 * 32 + c];
        ushort4 v3 = H[(size_t)s3 * 32 + c];
        a0 += bf2f(v0.x) + bf2f(v1.x) + bf2f(v2.x) + bf2f(v3.x);
        a1 += bf2f(v0.y) + bf2f(v1.y) + bf2f(v2.y) + bf2f(v3.y);
        a2 += bf2f(v0.z) + bf2f(v1.z) + bf2f(v2.z) + bf2f(v3.z);
        a3 += bf2f(v0.w) + bf2f(v1.w) + bf2f(v2.w) + bf2f(v3.w);
    }
    for (; j < e1; ++j) {
        int s = csr[j];
        ushort4 v = H[(size_t)s * 32 + c];
        a0 += bf2f(v.x); a1 += bf2f(v.y); a2 += bf2f(v.z); a3 += bf2f(v.w);
    }
    float di = dinv[node];
    float4 b = *(const float4*)(bcat + c * 4);
    float r0 = fmaxf(di * a0 + b.x, 0.f);
    float r1 = fmaxf(di * a1 + b.y, 0.f);
    float r2 = fmaxf(di * a2 + b.z, 0.f);
    float r3 = fmaxf(di * a3 + b.w, 0.f);
    r0 += __shfl_xor(r0, 8);  r1 += __shfl_xor(r1, 8);  r2 += __shfl_xor(r2, 8);  r3 += __shfl_xor(r3, 8);
    r0 += __shfl_xor(r0, 16); r1 += __shfl_xor(r1, 16); r2 += __shfl_xor(r2, 16); r3 += __shfl_xor(r3, 16);
    if ((c & 24) == 0) {   // lanes c=0..7 hold block-sums for feats 4c..4c+3
        ushort4 o;
        o.x = f2bf(r0 * di); o.y = f2bf(r1 * di); o.z = f2bf(r2 * di); o.w = f2bf(r3 * di);
        *(ushort4*)(xsp + (size_t)node * 32 + c * 4) = o;
    }
}

// ---------------- aggregation 32 (bf16 gather, unroll-4 MLP) -> axs f32 ----------------
// xsp pre-scaled by dinv[src]; 4 lanes/node, 16B loads (8 feats each).

__global__ __launch_bounds__(256) void agg32(const ushort* __restrict__ xsp, const float* __restrict__ dinv,
                                             const int* __restrict__ offs, const int* __restrict__ csr,
                                             float* __restrict__ axs, int N) {
    int t = blockIdx.x * 256 + threadIdx.x;
    int node = t >> 2, l = t & 3;
    if (node >= N) return;
    const short8* Xr = (const short8*)xsp;   // [N][4] chunks of 8 bf16
    short8 h = Xr[(size_t)node * 4 + l];
    float a[8];
    #pragma unroll
    for (int i = 0; i < 8; ++i) a[i] = bf2f((ushort)h[i]);
    int j = offs[node];
    int e1 = offs[node + 1];
    int jend = j + ((e1 - j) & ~3);
    for (; j < jend; j += 4) {
        int s0 = csr[j], s1 = csr[j + 1], s2 = csr[j + 2], s3 = csr[j + 3];
        short8 v0 = Xr[(size_t)s0 * 4 + l];
        short8 v1 = Xr[(size_t)s1 * 4 + l];
        short8 v2 = Xr[(size_t)s2 * 4 + l];
        short8 v3 = Xr[(size_t)s3 * 4 + l];
        #pragma unroll
        for (int i = 0; i < 8; ++i)
            a[i] += bf2f((ushort)v0[i]) + bf2f((ushort)v1[i]) + bf2f((ushort)v2[i]) + bf2f((ushort)v3[i]);
    }
    for (; j < e1; ++j) {
        int s = csr[j];
        short8 v = Xr[(size_t)s * 4 + l];
        #pragma unroll
        for (int i = 0; i < 8; ++i) a[i] += bf2f((ushort)v[i]);
    }
    float di = dinv[node];
    float4 o0 = make_float4(a[0] * di, a[1] * di, a[2] * di, a[3] * di);
    float4 o1 = make_float4(a[4] * di, a[5] * di, a[6] * di, a[7] * di);
    float* dst = axs + (size_t)node * 32 + l * 8;
    *(float4*)dst = o0;
    *(float4*)(dst + 4) = o1;
}

// ---------------- final: logits = axs @ W3s + b3s ; log_softmax ----------------

__global__ __launch_bounds__(256) void final_kernel(const float* __restrict__ axs, const float* __restrict__ W3s,
                                                    const float* __restrict__ b3s, float* __restrict__ out, int N) {
    __shared__ float w[32 * 40];
    __shared__ float b[40];
    int tid = threadIdx.x;
    for (int i = tid; i < 1280; i += 256) w[i] = W3s[i];
    if (tid < 40) b[tid] = b3s[tid];
    __syncthreads();
    int i = blockIdx.x * 256 + tid;
    if (i >= N) return;
    float a[32];
    #pragma unroll
    for (int q = 0; q < 8; ++q) {
        float4 v = *(const float4*)(axs + (size_t)i * 32 + q * 4);
        a[q * 4] = v.x; a[q * 4 + 1] = v.y; a[q * 4 + 2] = v.z; a[q * 4 + 3] = v.w;
    }
    float acc[40];
    #pragma unroll
    for (int c = 0; c < 40; ++c) acc[c] = b[c];
    #pragma unroll
    for (int k = 0; k < 32; ++k) {
        float av = a[k];
        #pragma unroll
        for (int c = 0; c < 40; ++c) acc[c] += av * w[k * 40 + c];
    }
    float m = acc[0];
    #pragma unroll
    for (int c = 1; c < 40; ++c) m = fmaxf(m, acc[c]);
    float sum = 0.f;
    #pragma unroll
    for (int c = 0; c < 40; ++c) sum += expf(acc[c] - m);
    float lg = m + logf(sum);
    #pragma unroll
    for (int c = 0; c < 40; ++c) out[(size_t)i * 40 + c] = acc[c] - lg;
}

// ---------------- launch ----------------

extern "C" void kernel_launch(void* const* d_in, const int* in_sizes, int n_in,
                              void* d_out, int out_size, void* d_ws, size_t ws_size,
                              hipStream_t stream) {
    const float* x   = (const float*)d_in[0];
    const int*   ei  = (const int*)d_in[1];
    const float* W1a = (const float*)d_in[2];  const float* b1a = (const float*)d_in[3];
    const float* W1b = (const float*)d_in[4];  const float* b1b = (const float*)d_in[5];
    const float* W2a = (const float*)d_in[6];  const float* b2a = (const float*)d_in[7];
    const float* W2b = (const float*)d_in[8];  const float* b2b = (const float*)d_in[9];
    const float* W3a = (const float*)d_in[10]; const float* b3a = (const float*)d_in[11];
    const float* W3b = (const float*)d_in[12]; const float* b3b = (const float*)d_in[13];

    int N = in_sizes[0] / 512;
    int E = in_sizes[1] / 2;
    const int* srcv = ei;
    const int* dstv = ei + E;

    char* ws = (char*)d_ws;
    size_t off = 0;
    auto alloc = [&](size_t bytes) { void* p = ws + off; off = (off + bytes + 255) & ~(size_t)255; return p; };
    int*    cnt    = (int*)   alloc((size_t)N * 4);
    int*    cursor = (int*)   alloc((size_t)N * 4);
    int*    offs   = (int*)   alloc((size_t)(N + 1) * 4);
    float*  dinv   = (float*) alloc((size_t)N * 4);
    int*    csr    = (int*)   alloc((size_t)E * 4);
    ushort* Wt     = (ushort*)alloc(128 * 512 * 2);
    float*  bcat   = (float*) alloc(128 * 4);
    float*  W3s    = (float*) alloc(1280 * 4);
    float*  b3s    = (float*) alloc(40 * 4);
    ushort* HWp    = (ushort*)alloc((size_t)N * 128 * 2);   // [N][128] bf16
    ushort* xsp    = (ushort*)alloc((size_t)N * 32 * 2);    // [N][32] bf16
    float*  axs    = (float*) alloc((size_t)N * 32 * 4);

    hipMemsetAsync(cnt, 0, (size_t)N * 4, stream);
    hipMemsetAsync(cursor, 0, (size_t)N * 4, stream);

    count_kernel<<<2048, 256, 0, stream>>>(dstv, cnt, E);
    dinv_kernel<<<(N + 255) / 256, 256, 0, stream>>>(cnt, dinv, N);
    scan_kernel<<<1, 1024, 0, stream>>>(cnt, offs, N);
    scatter_kernel<<<2048, 256, 0, stream>>>(srcv, dstv, offs, cursor, csr, E, N);
    prep_kernel<<<256, 256, 0, stream>>>(W1a, W1b, W2a, W2b, b1a, b1b, b2a, b2b,
                                         W3a, W3b, b3a, b3b, Wt, bcat, W3s, b3s);
    gemm_mfma<<<(N + GBM - 1) / GBM, 256, 0, stream>>>(x, Wt, dinv, HWp, N);
    agg128<<<((size_t)N * 32 + 255) / 256, 256, 0, stream>>>(HWp, dinv, offs, csr, bcat, xsp, N);
    agg32<<<((size_t)N * 4 + 255) / 256, 256, 0, stream>>>(xsp, dinv, offs, csr, axs, N);
    final_kernel<<<(N + 255) / 256, 256, 0, stream>>>(axs, W3s, b3s, (float*)d_out, N);
}